// Round 6
// baseline (453.779 us; speedup 1.0000x reference)
//
#include <hip/hip_runtime.h>
#include <math.h>

#define N_ROWS   65536
#define DIM      256
#define KCODES   1024
#define Q_SIZE   (N_ROWS * DIM)          // 16777216
#define OUT_LOSS Q_SIZE
#define OUT_PERP (Q_SIZE + 1)
#define OUT_IDX  (Q_SIZE + 2)

// flag threshold (original d2 units): > 2*ulp(256) + slop. Same as passing rounds.
#define TAU  1.25e-4f
// same threshold in scaled-score units (s' = 2^20 * s)
#define TAUP 131.072f

// ws layout (bytes)
#define WS_LOSS   0        // double
#define WS_RCNT   8        // int
#define WS_E2     16       // float[1024]  original units
#define WS_E2P    4112     // float[1024]  scaled by 2^20
#define WS_COUNTS 8208     // int[1024]
#define WS_IDX    12304    // int[65536]
#define WS_RLIST  274448   // int[65536]
#define WS_ET     536592   // float[262144]   E^T fp32 (refine)
#define WS_EH     1585168  // _Float16[262144] f16(1024*E)      [code][d]
#define WS_EL     2109456  // _Float16[262144] f16(1024*E - Eh) [code][d]
// end: 2633744 bytes

typedef _Float16 half8 __attribute__((ext_vector_type(8)));
typedef _Float16 half4 __attribute__((ext_vector_type(4)));
typedef float    f32x4 __attribute__((ext_vector_type(4)));

#define ROWB 1040   // LDS bytes per row: 512 (xh) + 512 (xl) + 16 pad (bank balance)
#define RPB  32     // rows per block (round 6: was 64; halved for occupancy)

// ---------------------------------------------------------------------------
// prep: e2, e2p, Et (fp32 transpose, refine), Eh/El f16 split; zero accums
// grid 1024 x 256
__global__ void k_prep(const float* __restrict__ E, float* __restrict__ e2,
                       float* __restrict__ e2p, float* __restrict__ Et,
                       _Float16* __restrict__ Eh, _Float16* __restrict__ El,
                       int* __restrict__ counts, double* __restrict__ loss,
                       int* __restrict__ rcnt) {
    int b = blockIdx.x, t = threadIdx.x;
    __shared__ double red[256];
    float v = E[b * DIM + t];
    red[t] = (double)v * (double)v;

    float ve = v * 1024.0f;               // exact scaling
    _Float16 h = (_Float16)ve;
    _Float16 l = (_Float16)(ve - (float)h);
    Eh[b * DIM + t] = h;
    El[b * DIM + t] = l;

    __syncthreads();
    for (int s = 128; s > 0; s >>= 1) {
        if (t < s) red[t] += red[t + s];
        __syncthreads();
    }
    if (t == 0) { e2[b] = (float)red[0]; e2p[b] = (float)(red[0] * 1048576.0); }

    int o = b * 256 + t;
    int d = o >> 10, k = o & 1023;
    Et[o] = E[k * DIM + d];

    if (b < 4) counts[b * 256 + t] = 0;
    if (b == 0 && t == 0) { *loss = 0.0; *rcnt = 0; }
}

// ---------------------------------------------------------------------------
// main: MFMA ranking. Block = 32 rows, 4 waves; wave w owns codes [w*256, w*256+256).
// dot' = xh*Eh + xl*Eh + xh*El (f16 3-split of 1024-scaled problem).
// s' = e2' - 2048*dot' ; per-lane top-2 -> butterfly -> cross-wave LDS merge.
// Round-6 sizing: 32 rows/block, wave tile 2mt x 4nt -> ~140 VGPR live state;
// (256,3) caps at 170 with margin (round-4 lesson: only cap with headroom).
// LDS 33.3 KB -> 4 blocks/CU LDS-wise; target 3 waves/SIMD residency.
// grid 2048 x 256
__launch_bounds__(256, 3)
__global__ void k_main(const float* __restrict__ X, const _Float16* __restrict__ Eh,
                       const _Float16* __restrict__ El, const float* __restrict__ e2p,
                       int* __restrict__ idx_ws, int* __restrict__ rlist,
                       int* __restrict__ rcnt) {
    __shared__ __align__(16) char sA[RPB * ROWB];   // 33280 B
    const int tid  = threadIdx.x;
    const int wid  = tid >> 6;
    const int lane = tid & 63;
    const int c16  = lane & 15;
    const int kg   = lane >> 4;          // 0..3
    const int rb   = blockIdx.x * RPB;

    // ---- stage X -> f16 hi/lo split in LDS (coalesced float4 reads) ----
    {
        const float4* Xg = (const float4*)(X + (size_t)rb * DIM);
        #pragma unroll
        for (int it = 0; it < 8; ++it) {
            int f = it * 256 + tid;
            int row = f >> 6, d4 = f & 63;
            float4 v = Xg[(size_t)row * 64 + d4];
            _Float16 h0 = (_Float16)v.x, h1 = (_Float16)v.y,
                     h2 = (_Float16)v.z, h3 = (_Float16)v.w;
            half4 hh = {h0, h1, h2, h3};
            half4 ll = {(_Float16)(v.x - (float)h0), (_Float16)(v.y - (float)h1),
                        (_Float16)(v.z - (float)h2), (_Float16)(v.w - (float)h3)};
            int base = row * ROWB + d4 * 8;
            *(half4*)(sA + base)       = hh;
            *(half4*)(sA + base + 512) = ll;
        }
    }
    __syncthreads();

    int Abase[2];
    #pragma unroll
    for (int mt = 0; mt < 2; ++mt) Abase[mt] = (mt * 16 + c16) * ROWB + kg * 16;

    float tb1[8], tb2[8];
    int   ti1[8];
    #pragma unroll
    for (int i = 0; i < 8; ++i) { tb1[i] = 3.4e38f; tb2[i] = 3.4e38f; ti1[i] = 0; }

    const int cw = wid * 256;
    const int k8 = kg * 8;

    for (int cb = 0; cb < 4; ++cb) {
        const int cbase = cw + cb * 64;
        const int c0 = cbase + c16;
        const _Float16* bhp = Eh + (size_t)c0 * 256 + k8;
        const _Float16* blp = El + (size_t)c0 * 256 + k8;

        f32x4 acc[2][4];
        #pragma unroll
        for (int mt = 0; mt < 2; ++mt)
            #pragma unroll
            for (int nt = 0; nt < 4; ++nt) acc[mt][nt] = 0.0f;

        // phase 1: (xh + xl) * Eh   — B loaded once per kk, used twice
        #pragma unroll
        for (int kk = 0; kk < 8; ++kk) {
            half8 b0 = *(const half8*)(bhp + (size_t)0 * 4096 + kk * 32);
            half8 b1 = *(const half8*)(bhp + (size_t)1 * 4096 + kk * 32);
            half8 b2 = *(const half8*)(bhp + (size_t)2 * 4096 + kk * 32);
            half8 b3 = *(const half8*)(bhp + (size_t)3 * 4096 + kk * 32);
            half8 ah[2], al[2];
            #pragma unroll
            for (int mt = 0; mt < 2; ++mt) {
                ah[mt] = *(const half8*)(sA + Abase[mt] + kk * 64);
                al[mt] = *(const half8*)(sA + Abase[mt] + 512 + kk * 64);
            }
            #pragma unroll
            for (int mt = 0; mt < 2; ++mt) {
                acc[mt][0] = __builtin_amdgcn_mfma_f32_16x16x32_f16(ah[mt], b0, acc[mt][0], 0, 0, 0);
                acc[mt][1] = __builtin_amdgcn_mfma_f32_16x16x32_f16(ah[mt], b1, acc[mt][1], 0, 0, 0);
                acc[mt][2] = __builtin_amdgcn_mfma_f32_16x16x32_f16(ah[mt], b2, acc[mt][2], 0, 0, 0);
                acc[mt][3] = __builtin_amdgcn_mfma_f32_16x16x32_f16(ah[mt], b3, acc[mt][3], 0, 0, 0);
            }
            #pragma unroll
            for (int mt = 0; mt < 2; ++mt) {
                acc[mt][0] = __builtin_amdgcn_mfma_f32_16x16x32_f16(al[mt], b0, acc[mt][0], 0, 0, 0);
                acc[mt][1] = __builtin_amdgcn_mfma_f32_16x16x32_f16(al[mt], b1, acc[mt][1], 0, 0, 0);
                acc[mt][2] = __builtin_amdgcn_mfma_f32_16x16x32_f16(al[mt], b2, acc[mt][2], 0, 0, 0);
                acc[mt][3] = __builtin_amdgcn_mfma_f32_16x16x32_f16(al[mt], b3, acc[mt][3], 0, 0, 0);
            }
        }
        // phase 2: xh * El
        #pragma unroll
        for (int kk = 0; kk < 8; ++kk) {
            half8 b0 = *(const half8*)(blp + (size_t)0 * 4096 + kk * 32);
            half8 b1 = *(const half8*)(blp + (size_t)1 * 4096 + kk * 32);
            half8 b2 = *(const half8*)(blp + (size_t)2 * 4096 + kk * 32);
            half8 b3 = *(const half8*)(blp + (size_t)3 * 4096 + kk * 32);
            half8 ah[2];
            #pragma unroll
            for (int mt = 0; mt < 2; ++mt)
                ah[mt] = *(const half8*)(sA + Abase[mt] + kk * 64);
            #pragma unroll
            for (int mt = 0; mt < 2; ++mt) {
                acc[mt][0] = __builtin_amdgcn_mfma_f32_16x16x32_f16(ah[mt], b0, acc[mt][0], 0, 0, 0);
                acc[mt][1] = __builtin_amdgcn_mfma_f32_16x16x32_f16(ah[mt], b1, acc[mt][1], 0, 0, 0);
                acc[mt][2] = __builtin_amdgcn_mfma_f32_16x16x32_f16(ah[mt], b2, acc[mt][2], 0, 0, 0);
                acc[mt][3] = __builtin_amdgcn_mfma_f32_16x16x32_f16(ah[mt], b3, acc[mt][3], 0, 0, 0);
            }
        }

        // epilogue: s' = e2' - 2048*dot', sorted-insert top-2 per (row seen by lane)
        float e2v[4];
        #pragma unroll
        for (int nt = 0; nt < 4; ++nt) e2v[nt] = e2p[c0 + nt * 16];
        #pragma unroll
        for (int mt = 0; mt < 2; ++mt)
            #pragma unroll
            for (int nt = 0; nt < 4; ++nt) {
                int code = cbase + nt * 16 + c16;
                #pragma unroll
                for (int r = 0; r < 4; ++r) {
                    float s = fmaf(-2048.0f, acc[mt][nt][r], e2v[nt]);
                    int ix = mt * 4 + r;
                    float hi = fmaxf(tb1[ix], s);
                    tb2[ix] = fminf(tb2[ix], hi);
                    bool lt = s < tb1[ix];
                    tb1[ix] = lt ? s : tb1[ix];
                    ti1[ix] = lt ? code : ti1[ix];
                }
            }
    }

    // ---- butterfly merge across the 16 col-lanes of each kg group ----
    #pragma unroll
    for (int ix = 0; ix < 8; ++ix) {
        float v1 = tb1[ix], v2 = tb2[ix];
        int   j1 = ti1[ix];
        #pragma unroll
        for (int m = 1; m < 16; m <<= 1) {
            float ov1 = __shfl_xor(v1, m, 64);
            int   oj1 = __shfl_xor(j1, m, 64);
            float ov2 = __shfl_xor(v2, m, 64);
            bool take = (ov1 < v1) || (ov1 == v1 && oj1 < j1);
            float losr = take ? v1 : ov1;
            v1 = take ? ov1 : v1;
            j1 = take ? oj1 : j1;
            v2 = fminf(fminf(v2, ov2), losr);
        }
        tb1[ix] = v1; tb2[ix] = v2; ti1[ix] = j1;
    }

    // ---- cross-wave merge via LDS (reuse sA) ----
    __syncthreads();
    float* mB1 = (float*)sA;            // [32][4]
    float* mB2 = (float*)(sA + 512);    // [32][4]
    int*   mI1 = (int*)(sA + 1024);     // [32][4]
    #pragma unroll
    for (int ix = 0; ix < 8; ++ix) {
        if (c16 == ix) {
            int row = (ix >> 2) * 16 + kg * 4 + (ix & 3);
            mB1[row * 4 + wid] = tb1[ix];
            mB2[row * 4 + wid] = tb2[ix];
            mI1[row * 4 + wid] = ti1[ix];
        }
    }
    __syncthreads();
    if (tid < RPB) {
        float m1 = 3.4e38f, m2 = 3.4e38f;
        int mi = 0;
        #pragma unroll
        for (int w = 0; w < 4; ++w) {
            float v = mB1[tid * 4 + w];
            int  id = mI1[tid * 4 + w];
            float u = mB2[tid * 4 + w];
            bool take = (v < m1) || (v == m1 && id < mi);
            float losr = take ? m1 : v;
            m1 = take ? v : m1;
            mi = take ? id : mi;
            m2 = fminf(fminf(m2, u), losr);
        }
        int g = rb + tid;
        idx_ws[g] = mi;
        if (m2 - m1 < TAUP) {
            int slot = atomicAdd(rcnt, 1);
            rlist[slot] = g;
        }
    }
}

// ---------------------------------------------------------------------------
// refine: replicate reference fp32 pipeline exactly for flagged rows (unchanged)
// grid 512 x 256
__global__ void k_refine(const float* __restrict__ X, const float* __restrict__ Et,
                         const float* __restrict__ e2,
                         const int* __restrict__ rlist, const int* __restrict__ rcnt,
                         int* __restrict__ idx_ws) {
    __shared__ float  xs[256];
    __shared__ double dred[256];
    __shared__ float  rv[256];
    __shared__ int    ri[256];
    __shared__ float  x2s;
    const int cnt = *rcnt;
    const int t = threadIdx.x;
    for (int e = blockIdx.x; e < cnt; e += gridDim.x) {
        int row = rlist[e];
        __syncthreads();
        if (t < 64) ((float4*)xs)[t] = ((const float4*)(X + (size_t)row * DIM))[t];
        __syncthreads();
        {
            float xv = xs[t];
            dred[t] = (double)xv * (double)xv;
            __syncthreads();
            for (int s = 128; s > 0; s >>= 1) {
                if (t < s) dred[t] += dred[t + s];
                __syncthreads();
            }
            if (t == 0) x2s = (float)dred[0];
            __syncthreads();
        }
        const float x2_32 = x2s;

        double acc[4] = {0.0, 0.0, 0.0, 0.0};
        for (int d = 0; d < DIM; ++d) {
            double xv = (double)xs[d];
            acc[0] += xv * (double)Et[d * KCODES + t];
            acc[1] += xv * (double)Et[d * KCODES + 256 + t];
            acc[2] += xv * (double)Et[d * KCODES + 512 + t];
            acc[3] += xv * (double)Et[d * KCODES + 768 + t];
        }
        float best = 3.4e38f;
        int   bk = 0;
        #pragma unroll
        for (int seg = 0; seg < 4; ++seg) {
            int k = seg * 256 + t;
            float M  = (float)acc[seg];
            float a  = x2_32 + e2[k];
            float d2 = fmaf(-2.f, M, a);
            if (d2 < best) { best = d2; bk = k; }
        }
        rv[t] = best; ri[t] = bk;
        __syncthreads();
        for (int s = 128; s > 0; s >>= 1) {
            if (t < s) {
                float ov = rv[t + s]; int oi = ri[t + s];
                if (ov < rv[t] || (ov == rv[t] && oi < ri[t])) { rv[t] = ov; ri[t] = oi; }
            }
            __syncthreads();
        }
        if (t == 0) idx_ws[row] = ri[0];
    }
}

// ---------------------------------------------------------------------------
// out: quantized rows, index output, loss, histogram. One fp64 atomic/block.
// grid 1024 x 256
__launch_bounds__(256)
__global__ void k_out(const float* __restrict__ X, const float* __restrict__ E,
                      const int* __restrict__ idx_ws, float* __restrict__ out,
                      int* __restrict__ counts, double* __restrict__ loss) {
    const int tid = threadIdx.x;
    const int w = tid >> 6, lane = tid & 63;
    const int rbase = blockIdx.x * 64;
    double ls = 0.0;
    #pragma unroll 4
    for (int it = 0; it < 16; ++it) {
        const int row = rbase + it * 4 + w;
        const int k = idx_ws[row];
        float4 q = ((const float4*)(E + (size_t)k * DIM))[lane];
        float4 x = ((const float4*)(X + (size_t)row * DIM))[lane];
        ((float4*)(out + (size_t)row * DIM))[lane] = q;
        double d0 = (double)q.x - (double)x.x;
        double d1 = (double)q.y - (double)x.y;
        double d2 = (double)q.z - (double)x.z;
        double d3 = (double)q.w - (double)x.w;
        ls += d0 * d0 + d1 * d1 + d2 * d2 + d3 * d3;
        if (lane == 0) {
            atomicAdd(&counts[k], 1);
            out[OUT_IDX + row] = (float)k;
        }
    }
    __shared__ double red[256];
    red[tid] = ls;
    __syncthreads();
    for (int s = 128; s > 0; s >>= 1) {
        if (tid < s) red[tid] += red[tid + s];
        __syncthreads();
    }
    if (tid == 0) atomicAdd(loss, red[0]);
}

// ---------------------------------------------------------------------------
// fin: scalars
__global__ void k_fin(const int* __restrict__ counts, const double* __restrict__ loss,
                      float* __restrict__ out) {
    int t = threadIdx.x;
    __shared__ double red[256];
    double h = 0.0;
    #pragma unroll
    for (int i = 0; i < 4; ++i) {
        double p = (double)counts[t + i * 256] / (double)N_ROWS;
        h += p * log(p + 1e-10);
    }
    red[t] = h;
    __syncthreads();
    for (int s = 128; s > 0; s >>= 1) {
        if (t < s) red[t] += red[t + s];
        __syncthreads();
    }
    if (t == 0) {
        out[OUT_PERP] = (float)exp(-red[0]);
        out[OUT_LOSS] = (float)((*loss) / (double)Q_SIZE * 1.25);
    }
}

// ---------------------------------------------------------------------------
extern "C" void kernel_launch(void* const* d_in, const int* in_sizes, int n_in,
                              void* d_out, int out_size, void* d_ws, size_t ws_size,
                              hipStream_t stream) {
    (void)in_sizes; (void)n_in; (void)out_size; (void)ws_size;
    const float* X = (const float*)d_in[0];
    const float* E = (const float*)d_in[1];
    float* out = (float*)d_out;
    char* ws = (char*)d_ws;

    double*    loss   = (double*)(ws + WS_LOSS);
    int*       rcnt   = (int*)(ws + WS_RCNT);
    float*     e2     = (float*)(ws + WS_E2);
    float*     e2p    = (float*)(ws + WS_E2P);
    int*       counts = (int*)(ws + WS_COUNTS);
    int*       idx_ws = (int*)(ws + WS_IDX);
    int*       rlist  = (int*)(ws + WS_RLIST);
    float*     Et     = (float*)(ws + WS_ET);
    _Float16*  Ehp    = (_Float16*)(ws + WS_EH);
    _Float16*  Elp    = (_Float16*)(ws + WS_EL);

    k_prep<<<1024, 256, 0, stream>>>(E, e2, e2p, Et, Ehp, Elp, counts, loss, rcnt);
    k_main<<<N_ROWS / RPB, 256, 0, stream>>>(X, Ehp, Elp, e2p, idx_ws, rlist, rcnt);
    k_refine<<<512, 256, 0, stream>>>(X, Et, e2, rlist, rcnt, idx_ws);
    k_out<<<1024, 256, 0, stream>>>(X, E, idx_ws, out, counts, loss);
    k_fin<<<1, 256, 0, stream>>>(counts, loss, out);
}

// Round 7
// 392.427 us; speedup vs baseline: 1.1563x; 1.1563x over previous
//
#include <hip/hip_runtime.h>
#include <math.h>

#define N_ROWS   65536
#define DIM      256
#define KCODES   1024
#define Q_SIZE   (N_ROWS * DIM)          // 16777216
#define OUT_LOSS Q_SIZE
#define OUT_PERP (Q_SIZE + 1)
#define OUT_IDX  (Q_SIZE + 2)

// flag threshold (original d2 units): > 2*ulp(256) + slop. Same as passing rounds.
#define TAU  1.25e-4f
// same threshold in scaled-score units (s' = 2^20 * s)
#define TAUP 131.072f

// ws layout (bytes)
#define WS_LOSS   0        // double
#define WS_RCNT   8        // int
#define WS_E2     16       // float[1024]  original units
#define WS_E2P    4112     // float[1024]  scaled by 2^20
#define WS_COUNTS 8208     // int[1024]
#define WS_IDX    12304    // int[65536]
#define WS_RLIST  274448   // int[65536]
#define WS_ET     536592   // float[262144]   E^T fp32 (refine)
#define WS_EH     1585168  // _Float16[262144] f16(1024*E)      [code][d]
#define WS_EL     2109456  // _Float16[262144] f16(1024*E - Eh) [code][d]
// end: 2633744 bytes

typedef _Float16 half8 __attribute__((ext_vector_type(8)));
typedef _Float16 half4 __attribute__((ext_vector_type(4)));
typedef float    f32x4 __attribute__((ext_vector_type(4)));

#define ROWB 1040   // LDS bytes per row: 512 (xh) + 512 (xl) + 16 pad (bank balance)
#define RPB  32     // rows per block

// ---------------------------------------------------------------------------
// prep: e2, e2p, Et (fp32 transpose, refine), Eh/El f16 split; zero accums
// grid 1024 x 256
__global__ void k_prep(const float* __restrict__ E, float* __restrict__ e2,
                       float* __restrict__ e2p, float* __restrict__ Et,
                       _Float16* __restrict__ Eh, _Float16* __restrict__ El,
                       int* __restrict__ counts, double* __restrict__ loss,
                       int* __restrict__ rcnt) {
    int b = blockIdx.x, t = threadIdx.x;
    __shared__ double red[256];
    float v = E[b * DIM + t];
    red[t] = (double)v * (double)v;

    float ve = v * 1024.0f;               // exact scaling
    _Float16 h = (_Float16)ve;
    _Float16 l = (_Float16)(ve - (float)h);
    Eh[b * DIM + t] = h;
    El[b * DIM + t] = l;

    __syncthreads();
    for (int s = 128; s > 0; s >>= 1) {
        if (t < s) red[t] += red[t + s];
        __syncthreads();
    }
    if (t == 0) { e2[b] = (float)red[0]; e2p[b] = (float)(red[0] * 1048576.0); }

    int o = b * 256 + t;
    int d = o >> 10, k = o & 1023;
    Et[o] = E[k * DIM + d];

    if (b < 4) counts[b * 256 + t] = 0;
    if (b == 0 && t == 0) { *loss = 0.0; *rcnt = 0; }
}

// ---------------------------------------------------------------------------
// main: MFMA ranking. Block = 32 rows, 4 waves; wave w owns codes [w*256, w*256+256).
// dot' = xh*Eh + xl*Eh + xh*El (f16 3-split of 1024-scaled problem).
// s' = e2' - 2048*dot' ; per-lane top-2 -> butterfly -> cross-wave LDS merge.
// OCCUPANCY NOTE (rounds 4-6): gfx950 unified VGPR/AGPR file — per-wave cost
// is VGPR_Count + acc AGPRs. Any __launch_bounds__ min-waves arg made the
// allocator starve the arch-VGPR side and spill ~150-250 MB to scratch
// (r4: 128+spill, r6: 84+spill). So: NO min-waves bound; live state kept
// small (acc 32 + B 16 + A 16 + top-2 24 + addr) so natural allocation
// lands ~150-170 arch + 32 acc -> 2-3 waves/SIMD spill-free.
// grid 2048 x 256
__launch_bounds__(256)
__global__ void k_main(const float* __restrict__ X, const _Float16* __restrict__ Eh,
                       const _Float16* __restrict__ El, const float* __restrict__ e2p,
                       int* __restrict__ idx_ws, int* __restrict__ rlist,
                       int* __restrict__ rcnt) {
    __shared__ __align__(16) char sA[RPB * ROWB];   // 33280 B
    const int tid  = threadIdx.x;
    const int wid  = tid >> 6;
    const int lane = tid & 63;
    const int c16  = lane & 15;
    const int kg   = lane >> 4;          // 0..3
    const int rb   = blockIdx.x * RPB;

    // ---- stage X -> f16 hi/lo split in LDS (coalesced float4 reads) ----
    {
        const float4* Xg = (const float4*)(X + (size_t)rb * DIM);
        #pragma unroll
        for (int it = 0; it < 8; ++it) {
            int f = it * 256 + tid;
            int row = f >> 6, d4 = f & 63;
            float4 v = Xg[(size_t)row * 64 + d4];
            _Float16 h0 = (_Float16)v.x, h1 = (_Float16)v.y,
                     h2 = (_Float16)v.z, h3 = (_Float16)v.w;
            half4 hh = {h0, h1, h2, h3};
            half4 ll = {(_Float16)(v.x - (float)h0), (_Float16)(v.y - (float)h1),
                        (_Float16)(v.z - (float)h2), (_Float16)(v.w - (float)h3)};
            int base = row * ROWB + d4 * 8;
            *(half4*)(sA + base)       = hh;
            *(half4*)(sA + base + 512) = ll;
        }
    }
    __syncthreads();

    int Abase[2];
    #pragma unroll
    for (int mt = 0; mt < 2; ++mt) Abase[mt] = (mt * 16 + c16) * ROWB + kg * 16;

    float tb1[8], tb2[8];
    int   ti1[8];
    #pragma unroll
    for (int i = 0; i < 8; ++i) { tb1[i] = 3.4e38f; tb2[i] = 3.4e38f; ti1[i] = 0; }

    const int cw = wid * 256;
    const int k8 = kg * 8;

    for (int cb = 0; cb < 4; ++cb) {
        const int cbase = cw + cb * 64;
        const int c0 = cbase + c16;
        const _Float16* bhp = Eh + (size_t)c0 * 256 + k8;
        const _Float16* blp = El + (size_t)c0 * 256 + k8;

        f32x4 acc[2][4];
        #pragma unroll
        for (int mt = 0; mt < 2; ++mt)
            #pragma unroll
            for (int nt = 0; nt < 4; ++nt) acc[mt][nt] = 0.0f;

        // phase 1: (xh + xl) * Eh   — B loaded once per kk, used twice
        #pragma unroll
        for (int kk = 0; kk < 8; ++kk) {
            half8 b0 = *(const half8*)(bhp + (size_t)0 * 4096 + kk * 32);
            half8 b1 = *(const half8*)(bhp + (size_t)1 * 4096 + kk * 32);
            half8 b2 = *(const half8*)(bhp + (size_t)2 * 4096 + kk * 32);
            half8 b3 = *(const half8*)(bhp + (size_t)3 * 4096 + kk * 32);
            half8 ah[2], al[2];
            #pragma unroll
            for (int mt = 0; mt < 2; ++mt) {
                ah[mt] = *(const half8*)(sA + Abase[mt] + kk * 64);
                al[mt] = *(const half8*)(sA + Abase[mt] + 512 + kk * 64);
            }
            #pragma unroll
            for (int mt = 0; mt < 2; ++mt) {
                acc[mt][0] = __builtin_amdgcn_mfma_f32_16x16x32_f16(ah[mt], b0, acc[mt][0], 0, 0, 0);
                acc[mt][1] = __builtin_amdgcn_mfma_f32_16x16x32_f16(ah[mt], b1, acc[mt][1], 0, 0, 0);
                acc[mt][2] = __builtin_amdgcn_mfma_f32_16x16x32_f16(ah[mt], b2, acc[mt][2], 0, 0, 0);
                acc[mt][3] = __builtin_amdgcn_mfma_f32_16x16x32_f16(ah[mt], b3, acc[mt][3], 0, 0, 0);
            }
            #pragma unroll
            for (int mt = 0; mt < 2; ++mt) {
                acc[mt][0] = __builtin_amdgcn_mfma_f32_16x16x32_f16(al[mt], b0, acc[mt][0], 0, 0, 0);
                acc[mt][1] = __builtin_amdgcn_mfma_f32_16x16x32_f16(al[mt], b1, acc[mt][1], 0, 0, 0);
                acc[mt][2] = __builtin_amdgcn_mfma_f32_16x16x32_f16(al[mt], b2, acc[mt][2], 0, 0, 0);
                acc[mt][3] = __builtin_amdgcn_mfma_f32_16x16x32_f16(al[mt], b3, acc[mt][3], 0, 0, 0);
            }
        }
        // phase 2: xh * El
        #pragma unroll
        for (int kk = 0; kk < 8; ++kk) {
            half8 b0 = *(const half8*)(blp + (size_t)0 * 4096 + kk * 32);
            half8 b1 = *(const half8*)(blp + (size_t)1 * 4096 + kk * 32);
            half8 b2 = *(const half8*)(blp + (size_t)2 * 4096 + kk * 32);
            half8 b3 = *(const half8*)(blp + (size_t)3 * 4096 + kk * 32);
            half8 ah[2];
            #pragma unroll
            for (int mt = 0; mt < 2; ++mt)
                ah[mt] = *(const half8*)(sA + Abase[mt] + kk * 64);
            #pragma unroll
            for (int mt = 0; mt < 2; ++mt) {
                acc[mt][0] = __builtin_amdgcn_mfma_f32_16x16x32_f16(ah[mt], b0, acc[mt][0], 0, 0, 0);
                acc[mt][1] = __builtin_amdgcn_mfma_f32_16x16x32_f16(ah[mt], b1, acc[mt][1], 0, 0, 0);
                acc[mt][2] = __builtin_amdgcn_mfma_f32_16x16x32_f16(ah[mt], b2, acc[mt][2], 0, 0, 0);
                acc[mt][3] = __builtin_amdgcn_mfma_f32_16x16x32_f16(ah[mt], b3, acc[mt][3], 0, 0, 0);
            }
        }

        // epilogue: s' = e2' - 2048*dot', sorted-insert top-2 per (row seen by lane)
        float e2v[4];
        #pragma unroll
        for (int nt = 0; nt < 4; ++nt) e2v[nt] = e2p[c0 + nt * 16];
        #pragma unroll
        for (int mt = 0; mt < 2; ++mt)
            #pragma unroll
            for (int nt = 0; nt < 4; ++nt) {
                int code = cbase + nt * 16 + c16;
                #pragma unroll
                for (int r = 0; r < 4; ++r) {
                    float s = fmaf(-2048.0f, acc[mt][nt][r], e2v[nt]);
                    int ix = mt * 4 + r;
                    float hi = fmaxf(tb1[ix], s);
                    tb2[ix] = fminf(tb2[ix], hi);
                    bool lt = s < tb1[ix];
                    tb1[ix] = lt ? s : tb1[ix];
                    ti1[ix] = lt ? code : ti1[ix];
                }
            }
    }

    // ---- butterfly merge across the 16 col-lanes of each kg group ----
    #pragma unroll
    for (int ix = 0; ix < 8; ++ix) {
        float v1 = tb1[ix], v2 = tb2[ix];
        int   j1 = ti1[ix];
        #pragma unroll
        for (int m = 1; m < 16; m <<= 1) {
            float ov1 = __shfl_xor(v1, m, 64);
            int   oj1 = __shfl_xor(j1, m, 64);
            float ov2 = __shfl_xor(v2, m, 64);
            bool take = (ov1 < v1) || (ov1 == v1 && oj1 < j1);
            float losr = take ? v1 : ov1;
            v1 = take ? ov1 : v1;
            j1 = take ? oj1 : j1;
            v2 = fminf(fminf(v2, ov2), losr);
        }
        tb1[ix] = v1; tb2[ix] = v2; ti1[ix] = j1;
    }

    // ---- cross-wave merge via LDS (reuse sA) ----
    __syncthreads();
    float* mB1 = (float*)sA;            // [32][4]
    float* mB2 = (float*)(sA + 512);    // [32][4]
    int*   mI1 = (int*)(sA + 1024);     // [32][4]
    #pragma unroll
    for (int ix = 0; ix < 8; ++ix) {
        if (c16 == ix) {
            int row = (ix >> 2) * 16 + kg * 4 + (ix & 3);
            mB1[row * 4 + wid] = tb1[ix];
            mB2[row * 4 + wid] = tb2[ix];
            mI1[row * 4 + wid] = ti1[ix];
        }
    }
    __syncthreads();
    if (tid < RPB) {
        float m1 = 3.4e38f, m2 = 3.4e38f;
        int mi = 0;
        #pragma unroll
        for (int w = 0; w < 4; ++w) {
            float v = mB1[tid * 4 + w];
            int  id = mI1[tid * 4 + w];
            float u = mB2[tid * 4 + w];
            bool take = (v < m1) || (v == m1 && id < mi);
            float losr = take ? m1 : v;
            m1 = take ? v : m1;
            mi = take ? id : mi;
            m2 = fminf(fminf(m2, u), losr);
        }
        int g = rb + tid;
        idx_ws[g] = mi;
        if (m2 - m1 < TAUP) {
            int slot = atomicAdd(rcnt, 1);
            rlist[slot] = g;
        }
    }
}

// ---------------------------------------------------------------------------
// refine: replicate reference fp32 pipeline exactly for flagged rows (unchanged)
// grid 512 x 256
__global__ void k_refine(const float* __restrict__ X, const float* __restrict__ Et,
                         const float* __restrict__ e2,
                         const int* __restrict__ rlist, const int* __restrict__ rcnt,
                         int* __restrict__ idx_ws) {
    __shared__ float  xs[256];
    __shared__ double dred[256];
    __shared__ float  rv[256];
    __shared__ int    ri[256];
    __shared__ float  x2s;
    const int cnt = *rcnt;
    const int t = threadIdx.x;
    for (int e = blockIdx.x; e < cnt; e += gridDim.x) {
        int row = rlist[e];
        __syncthreads();
        if (t < 64) ((float4*)xs)[t] = ((const float4*)(X + (size_t)row * DIM))[t];
        __syncthreads();
        {
            float xv = xs[t];
            dred[t] = (double)xv * (double)xv;
            __syncthreads();
            for (int s = 128; s > 0; s >>= 1) {
                if (t < s) dred[t] += dred[t + s];
                __syncthreads();
            }
            if (t == 0) x2s = (float)dred[0];
            __syncthreads();
        }
        const float x2_32 = x2s;

        double acc[4] = {0.0, 0.0, 0.0, 0.0};
        for (int d = 0; d < DIM; ++d) {
            double xv = (double)xs[d];
            acc[0] += xv * (double)Et[d * KCODES + t];
            acc[1] += xv * (double)Et[d * KCODES + 256 + t];
            acc[2] += xv * (double)Et[d * KCODES + 512 + t];
            acc[3] += xv * (double)Et[d * KCODES + 768 + t];
        }
        float best = 3.4e38f;
        int   bk = 0;
        #pragma unroll
        for (int seg = 0; seg < 4; ++seg) {
            int k = seg * 256 + t;
            float M  = (float)acc[seg];
            float a  = x2_32 + e2[k];
            float d2 = fmaf(-2.f, M, a);
            if (d2 < best) { best = d2; bk = k; }
        }
        rv[t] = best; ri[t] = bk;
        __syncthreads();
        for (int s = 128; s > 0; s >>= 1) {
            if (t < s) {
                float ov = rv[t + s]; int oi = ri[t + s];
                if (ov < rv[t] || (ov == rv[t] && oi < ri[t])) { rv[t] = ov; ri[t] = oi; }
            }
            __syncthreads();
        }
        if (t == 0) idx_ws[row] = ri[0];
    }
}

// ---------------------------------------------------------------------------
// out: quantized rows, index output, loss, histogram. One fp64 atomic/block.
// grid 1024 x 256
__launch_bounds__(256)
__global__ void k_out(const float* __restrict__ X, const float* __restrict__ E,
                      const int* __restrict__ idx_ws, float* __restrict__ out,
                      int* __restrict__ counts, double* __restrict__ loss) {
    const int tid = threadIdx.x;
    const int w = tid >> 6, lane = tid & 63;
    const int rbase = blockIdx.x * 64;
    double ls = 0.0;
    #pragma unroll 4
    for (int it = 0; it < 16; ++it) {
        const int row = rbase + it * 4 + w;
        const int k = idx_ws[row];
        float4 q = ((const float4*)(E + (size_t)k * DIM))[lane];
        float4 x = ((const float4*)(X + (size_t)row * DIM))[lane];
        ((float4*)(out + (size_t)row * DIM))[lane] = q;
        double d0 = (double)q.x - (double)x.x;
        double d1 = (double)q.y - (double)x.y;
        double d2 = (double)q.z - (double)x.z;
        double d3 = (double)q.w - (double)x.w;
        ls += d0 * d0 + d1 * d1 + d2 * d2 + d3 * d3;
        if (lane == 0) {
            atomicAdd(&counts[k], 1);
            out[OUT_IDX + row] = (float)k;
        }
    }
    __shared__ double red[256];
    red[tid] = ls;
    __syncthreads();
    for (int s = 128; s > 0; s >>= 1) {
        if (tid < s) red[tid] += red[tid + s];
        __syncthreads();
    }
    if (tid == 0) atomicAdd(loss, red[0]);
}

// ---------------------------------------------------------------------------
// fin: scalars
__global__ void k_fin(const int* __restrict__ counts, const double* __restrict__ loss,
                      float* __restrict__ out) {
    int t = threadIdx.x;
    __shared__ double red[256];
    double h = 0.0;
    #pragma unroll
    for (int i = 0; i < 4; ++i) {
        double p = (double)counts[t + i * 256] / (double)N_ROWS;
        h += p * log(p + 1e-10);
    }
    red[t] = h;
    __syncthreads();
    for (int s = 128; s > 0; s >>= 1) {
        if (t < s) red[t] += red[t + s];
        __syncthreads();
    }
    if (t == 0) {
        out[OUT_PERP] = (float)exp(-red[0]);
        out[OUT_LOSS] = (float)((*loss) / (double)Q_SIZE * 1.25);
    }
}

// ---------------------------------------------------------------------------
extern "C" void kernel_launch(void* const* d_in, const int* in_sizes, int n_in,
                              void* d_out, int out_size, void* d_ws, size_t ws_size,
                              hipStream_t stream) {
    (void)in_sizes; (void)n_in; (void)out_size; (void)ws_size;
    const float* X = (const float*)d_in[0];
    const float* E = (const float*)d_in[1];
    float* out = (float*)d_out;
    char* ws = (char*)d_ws;

    double*    loss   = (double*)(ws + WS_LOSS);
    int*       rcnt   = (int*)(ws + WS_RCNT);
    float*     e2     = (float*)(ws + WS_E2);
    float*     e2p    = (float*)(ws + WS_E2P);
    int*       counts = (int*)(ws + WS_COUNTS);
    int*       idx_ws = (int*)(ws + WS_IDX);
    int*       rlist  = (int*)(ws + WS_RLIST);
    float*     Et     = (float*)(ws + WS_ET);
    _Float16*  Ehp    = (_Float16*)(ws + WS_EH);
    _Float16*  Elp    = (_Float16*)(ws + WS_EL);

    k_prep<<<1024, 256, 0, stream>>>(E, e2, e2p, Et, Ehp, Elp, counts, loss, rcnt);
    k_main<<<N_ROWS / RPB, 256, 0, stream>>>(X, Ehp, Elp, e2p, idx_ws, rlist, rcnt);
    k_refine<<<512, 256, 0, stream>>>(X, Et, e2, rlist, rcnt, idx_ws);
    k_out<<<1024, 256, 0, stream>>>(X, E, idx_ws, out, counts, loss);
    k_fin<<<1, 256, 0, stream>>>(counts, loss, out);
}

// Round 8
// 242.762 us; speedup vs baseline: 1.8692x; 1.6165x over previous
//
#include <hip/hip_runtime.h>
#include <math.h>

#define N_ROWS   65536
#define DIM      256
#define KCODES   1024
#define Q_SIZE   (N_ROWS * DIM)          // 16777216
#define OUT_LOSS Q_SIZE
#define OUT_PERP (Q_SIZE + 1)
#define OUT_IDX  (Q_SIZE + 2)

// flag threshold in scaled-score units (s' = 2^20 * d2-units).
// Single-product ranking: per-score error 8-sigma ~ 56 s' (dropped xl*Eh + xh*El
// cross terms). Flag if observed gap < 64 (fp32 ref grid) + 2*60 + slack = 200.
// Unflagged => true gap >= 200-2*56 = 88 > 64 => reference provably agrees.
#define TAUP 200.0f

// ws layout (bytes)
#define WS_LOSS   0        // double
#define WS_RCNT   8        // int
#define WS_E2     16       // float[1024]  original units
#define WS_E2P    4112     // float[1024]  scaled by 2^20
#define WS_COUNTS 8208     // int[1024]
#define WS_IDX    12304    // int[65536]
#define WS_RLIST  274448   // int[65536]
#define WS_ET     536592   // float[262144]   E^T fp32 (refine)
#define WS_EH     1585168  // _Float16[262144] f16(1024*E)  [code][d]

typedef _Float16 half8 __attribute__((ext_vector_type(8)));
typedef _Float16 half4 __attribute__((ext_vector_type(4)));
typedef float    f32x4 __attribute__((ext_vector_type(4)));

#define ROWB 528    // LDS bytes per row: 512 (xh) + 16 pad (132 dwords: bank 4r pattern, 2-way max = free)
#define RPB  64     // rows per block (r5-proven geometry, 6:1 MFMA:B-load)

// ---------------------------------------------------------------------------
// prep: e2, e2p, Et (fp32 transpose, refine), Eh f16; zero accums
// grid 1024 x 256
__global__ void k_prep(const float* __restrict__ E, float* __restrict__ e2,
                       float* __restrict__ e2p, float* __restrict__ Et,
                       _Float16* __restrict__ Eh,
                       int* __restrict__ counts, double* __restrict__ loss,
                       int* __restrict__ rcnt) {
    int b = blockIdx.x, t = threadIdx.x;
    __shared__ double red[256];
    float v = E[b * DIM + t];
    red[t] = (double)v * (double)v;

    Eh[b * DIM + t] = (_Float16)(v * 1024.0f);   // exact scaling, RN to f16

    __syncthreads();
    for (int s = 128; s > 0; s >>= 1) {
        if (t < s) red[t] += red[t + s];
        __syncthreads();
    }
    if (t == 0) { e2[b] = (float)red[0]; e2p[b] = (float)(red[0] * 1048576.0); }

    int o = b * 256 + t;
    int d = o >> 10, k = o & 1023;
    Et[o] = E[k * DIM + d];

    if (b < 4) counts[b * 256 + t] = 0;
    if (b == 0 && t == 0) { *loss = 0.0; *rcnt = 0; }
}

// ---------------------------------------------------------------------------
// main: MFMA ranking, SINGLE f16 product xh*Eh (errors absorbed by TAUP+refine).
// Block = 64 rows, 4 waves; wave w owns codes [w*256, w*256+256), mt=4 x nt=4.
// s' = e2' - 2048*dot' ; per-lane top-2 -> butterfly -> cross-wave LDS merge.
// OCCUPANCY NOTE (r4-r7): never use a min-waves launch bound here — it starves
// the unified VGPR/AGPR allocator and spills 150-250 MB to scratch.
// grid 1024 x 256
__launch_bounds__(256)
__global__ void k_main(const float* __restrict__ X, const _Float16* __restrict__ Eh,
                       const float* __restrict__ e2p,
                       int* __restrict__ idx_ws, int* __restrict__ rlist,
                       int* __restrict__ rcnt) {
    __shared__ __align__(16) char sA[RPB * ROWB];   // 33792 B
    const int tid  = threadIdx.x;
    const int wid  = tid >> 6;
    const int lane = tid & 63;
    const int c16  = lane & 15;
    const int kg   = lane >> 4;          // 0..3
    const int rb   = blockIdx.x * RPB;

    // ---- stage X -> f16 (hi only) in LDS (coalesced float4 reads) ----
    {
        const float4* Xg = (const float4*)(X + (size_t)rb * DIM);
        #pragma unroll
        for (int it = 0; it < 16; ++it) {
            int f = it * 256 + tid;
            int row = f >> 6, d4 = f & 63;
            float4 v = Xg[(size_t)row * 64 + d4];
            half4 hh = {(_Float16)v.x, (_Float16)v.y, (_Float16)v.z, (_Float16)v.w};
            *(half4*)(sA + row * ROWB + d4 * 8) = hh;
        }
    }
    __syncthreads();

    int Abase[4];
    #pragma unroll
    for (int mt = 0; mt < 4; ++mt) Abase[mt] = (mt * 16 + c16) * ROWB + kg * 16;

    float tb1[16], tb2[16];
    int   ti1[16];
    #pragma unroll
    for (int i = 0; i < 16; ++i) { tb1[i] = 3.4e38f; tb2[i] = 3.4e38f; ti1[i] = 0; }

    const int cw = wid * 256;
    const int k8 = kg * 8;

    for (int cb = 0; cb < 4; ++cb) {
        const int cbase = cw + cb * 64;
        const int c0 = cbase + c16;
        const _Float16* bhp = Eh + (size_t)c0 * 256 + k8;

        f32x4 acc[4][4];
        #pragma unroll
        for (int mt = 0; mt < 4; ++mt)
            #pragma unroll
            for (int nt = 0; nt < 4; ++nt) acc[mt][nt] = 0.0f;

        #pragma unroll
        for (int kk = 0; kk < 8; ++kk) {
            half8 b0 = *(const half8*)(bhp + (size_t)0 * 4096 + kk * 32);
            half8 b1 = *(const half8*)(bhp + (size_t)1 * 4096 + kk * 32);
            half8 b2 = *(const half8*)(bhp + (size_t)2 * 4096 + kk * 32);
            half8 b3 = *(const half8*)(bhp + (size_t)3 * 4096 + kk * 32);
            half8 ah[4];
            #pragma unroll
            for (int mt = 0; mt < 4; ++mt)
                ah[mt] = *(const half8*)(sA + Abase[mt] + kk * 64);
            #pragma unroll
            for (int mt = 0; mt < 4; ++mt) {
                acc[mt][0] = __builtin_amdgcn_mfma_f32_16x16x32_f16(ah[mt], b0, acc[mt][0], 0, 0, 0);
                acc[mt][1] = __builtin_amdgcn_mfma_f32_16x16x32_f16(ah[mt], b1, acc[mt][1], 0, 0, 0);
                acc[mt][2] = __builtin_amdgcn_mfma_f32_16x16x32_f16(ah[mt], b2, acc[mt][2], 0, 0, 0);
                acc[mt][3] = __builtin_amdgcn_mfma_f32_16x16x32_f16(ah[mt], b3, acc[mt][3], 0, 0, 0);
            }
        }

        // epilogue: s' = e2' - 2048*dot', sorted-insert top-2 per (row seen by lane)
        float e2v[4];
        #pragma unroll
        for (int nt = 0; nt < 4; ++nt) e2v[nt] = e2p[c0 + nt * 16];
        #pragma unroll
        for (int mt = 0; mt < 4; ++mt)
            #pragma unroll
            for (int nt = 0; nt < 4; ++nt) {
                int code = cbase + nt * 16 + c16;
                #pragma unroll
                for (int r = 0; r < 4; ++r) {
                    float s = fmaf(-2048.0f, acc[mt][nt][r], e2v[nt]);
                    int ix = mt * 4 + r;
                    float hi = fmaxf(tb1[ix], s);
                    tb2[ix] = fminf(tb2[ix], hi);
                    bool lt = s < tb1[ix];
                    tb1[ix] = lt ? s : tb1[ix];
                    ti1[ix] = lt ? code : ti1[ix];
                }
            }
    }

    // ---- butterfly merge across the 16 col-lanes of each kg group ----
    #pragma unroll
    for (int ix = 0; ix < 16; ++ix) {
        float v1 = tb1[ix], v2 = tb2[ix];
        int   j1 = ti1[ix];
        #pragma unroll
        for (int m = 1; m < 16; m <<= 1) {
            float ov1 = __shfl_xor(v1, m, 64);
            int   oj1 = __shfl_xor(j1, m, 64);
            float ov2 = __shfl_xor(v2, m, 64);
            bool take = (ov1 < v1) || (ov1 == v1 && oj1 < j1);
            float losr = take ? v1 : ov1;
            v1 = take ? ov1 : v1;
            j1 = take ? oj1 : j1;
            v2 = fminf(fminf(v2, ov2), losr);
        }
        tb1[ix] = v1; tb2[ix] = v2; ti1[ix] = j1;
    }

    // ---- cross-wave merge via LDS (reuse sA) ----
    __syncthreads();
    float* mB1 = (float*)sA;            // [64][4]
    float* mB2 = (float*)(sA + 1024);   // [64][4]
    int*   mI1 = (int*)(sA + 2048);     // [64][4]
    #pragma unroll
    for (int ix = 0; ix < 16; ++ix) {
        if (c16 == ix) {
            int row = (ix >> 2) * 16 + kg * 4 + (ix & 3);
            mB1[row * 4 + wid] = tb1[ix];
            mB2[row * 4 + wid] = tb2[ix];
            mI1[row * 4 + wid] = ti1[ix];
        }
    }
    __syncthreads();
    if (tid < RPB) {
        float m1 = 3.4e38f, m2 = 3.4e38f;
        int mi = 0;
        #pragma unroll
        for (int w = 0; w < 4; ++w) {
            float v = mB1[tid * 4 + w];
            int  id = mI1[tid * 4 + w];
            float u = mB2[tid * 4 + w];
            bool take = (v < m1) || (v == m1 && id < mi);
            float losr = take ? m1 : v;
            m1 = take ? v : m1;
            mi = take ? id : mi;
            m2 = fminf(fminf(m2, u), losr);
        }
        int g = rb + tid;
        idx_ws[g] = mi;
        if (m2 - m1 < TAUP) {
            int slot = atomicAdd(rcnt, 1);
            rlist[slot] = g;
        }
    }
}

// ---------------------------------------------------------------------------
// refine: replicate reference fp32 pipeline exactly for flagged rows (unchanged
// logic; grid doubled to 1024 since TAUP widened -> ~1.5x more flagged rows)
__global__ void k_refine(const float* __restrict__ X, const float* __restrict__ Et,
                         const float* __restrict__ e2,
                         const int* __restrict__ rlist, const int* __restrict__ rcnt,
                         int* __restrict__ idx_ws) {
    __shared__ float  xs[256];
    __shared__ double dred[256];
    __shared__ float  rv[256];
    __shared__ int    ri[256];
    __shared__ float  x2s;
    const int cnt = *rcnt;
    const int t = threadIdx.x;
    for (int e = blockIdx.x; e < cnt; e += gridDim.x) {
        int row = rlist[e];
        __syncthreads();
        if (t < 64) ((float4*)xs)[t] = ((const float4*)(X + (size_t)row * DIM))[t];
        __syncthreads();
        {
            float xv = xs[t];
            dred[t] = (double)xv * (double)xv;
            __syncthreads();
            for (int s = 128; s > 0; s >>= 1) {
                if (t < s) dred[t] += dred[t + s];
                __syncthreads();
            }
            if (t == 0) x2s = (float)dred[0];
            __syncthreads();
        }
        const float x2_32 = x2s;

        double acc[4] = {0.0, 0.0, 0.0, 0.0};
        for (int d = 0; d < DIM; ++d) {
            double xv = (double)xs[d];
            acc[0] += xv * (double)Et[d * KCODES + t];
            acc[1] += xv * (double)Et[d * KCODES + 256 + t];
            acc[2] += xv * (double)Et[d * KCODES + 512 + t];
            acc[3] += xv * (double)Et[d * KCODES + 768 + t];
        }
        float best = 3.4e38f;
        int   bk = 0;
        #pragma unroll
        for (int seg = 0; seg < 4; ++seg) {
            int k = seg * 256 + t;
            float M  = (float)acc[seg];
            float a  = x2_32 + e2[k];
            float d2 = fmaf(-2.f, M, a);
            if (d2 < best) { best = d2; bk = k; }
        }
        rv[t] = best; ri[t] = bk;
        __syncthreads();
        for (int s = 128; s > 0; s >>= 1) {
            if (t < s) {
                float ov = rv[t + s]; int oi = ri[t + s];
                if (ov < rv[t] || (ov == rv[t] && oi < ri[t])) { rv[t] = ov; ri[t] = oi; }
            }
            __syncthreads();
        }
        if (t == 0) idx_ws[row] = ri[0];
    }
}

// ---------------------------------------------------------------------------
// out: quantized rows, index output, loss, histogram. One fp64 atomic/block.
// grid 1024 x 256
__launch_bounds__(256)
__global__ void k_out(const float* __restrict__ X, const float* __restrict__ E,
                      const int* __restrict__ idx_ws, float* __restrict__ out,
                      int* __restrict__ counts, double* __restrict__ loss) {
    const int tid = threadIdx.x;
    const int w = tid >> 6, lane = tid & 63;
    const int rbase = blockIdx.x * 64;
    double ls = 0.0;
    #pragma unroll 4
    for (int it = 0; it < 16; ++it) {
        const int row = rbase + it * 4 + w;
        const int k = idx_ws[row];
        float4 q = ((const float4*)(E + (size_t)k * DIM))[lane];
        float4 x = ((const float4*)(X + (size_t)row * DIM))[lane];
        ((float4*)(out + (size_t)row * DIM))[lane] = q;
        double d0 = (double)q.x - (double)x.x;
        double d1 = (double)q.y - (double)x.y;
        double d2 = (double)q.z - (double)x.z;
        double d3 = (double)q.w - (double)x.w;
        ls += d0 * d0 + d1 * d1 + d2 * d2 + d3 * d3;
        if (lane == 0) {
            atomicAdd(&counts[k], 1);
            out[OUT_IDX + row] = (float)k;
        }
    }
    __shared__ double red[256];
    red[tid] = ls;
    __syncthreads();
    for (int s = 128; s > 0; s >>= 1) {
        if (tid < s) red[tid] += red[tid + s];
        __syncthreads();
    }
    if (tid == 0) atomicAdd(loss, red[0]);
}

// ---------------------------------------------------------------------------
// fin: scalars
__global__ void k_fin(const int* __restrict__ counts, const double* __restrict__ loss,
                      float* __restrict__ out) {
    int t = threadIdx.x;
    __shared__ double red[256];
    double h = 0.0;
    #pragma unroll
    for (int i = 0; i < 4; ++i) {
        double p = (double)counts[t + i * 256] / (double)N_ROWS;
        h += p * log(p + 1e-10);
    }
    red[t] = h;
    __syncthreads();
    for (int s = 128; s > 0; s >>= 1) {
        if (t < s) red[t] += red[t + s];
        __syncthreads();
    }
    if (t == 0) {
        out[OUT_PERP] = (float)exp(-red[0]);
        out[OUT_LOSS] = (float)((*loss) / (double)Q_SIZE * 1.25);
    }
}

// ---------------------------------------------------------------------------
extern "C" void kernel_launch(void* const* d_in, const int* in_sizes, int n_in,
                              void* d_out, int out_size, void* d_ws, size_t ws_size,
                              hipStream_t stream) {
    (void)in_sizes; (void)n_in; (void)out_size; (void)ws_size;
    const float* X = (const float*)d_in[0];
    const float* E = (const float*)d_in[1];
    float* out = (float*)d_out;
    char* ws = (char*)d_ws;

    double*    loss   = (double*)(ws + WS_LOSS);
    int*       rcnt   = (int*)(ws + WS_RCNT);
    float*     e2     = (float*)(ws + WS_E2);
    float*     e2p    = (float*)(ws + WS_E2P);
    int*       counts = (int*)(ws + WS_COUNTS);
    int*       idx_ws = (int*)(ws + WS_IDX);
    int*       rlist  = (int*)(ws + WS_RLIST);
    float*     Et     = (float*)(ws + WS_ET);
    _Float16*  Ehp    = (_Float16*)(ws + WS_EH);

    k_prep<<<1024, 256, 0, stream>>>(E, e2, e2p, Et, Ehp, counts, loss, rcnt);
    k_main<<<N_ROWS / RPB, 256, 0, stream>>>(X, Ehp, e2p, idx_ws, rlist, rcnt);
    k_refine<<<1024, 256, 0, stream>>>(X, Et, e2, rlist, rcnt, idx_ws);
    k_out<<<1024, 256, 0, stream>>>(X, E, idx_ws, out, counts, loss);
    k_fin<<<1, 256, 0, stream>>>(counts, loss, out);
}